// Round 10
// baseline (169.841 us; speedup 1.0000x reference)
//
#include <hip/hip_runtime.h>
#include <math.h>

#define B_ 4
#define T_ 4096
#define C_ 1024
#define H_ 64
#define NROW (B_ * T_)  // 16384

typedef unsigned short u16;
typedef __attribute__((ext_vector_type(8))) short short8;
typedef __attribute__((ext_vector_type(4))) float floatx4;
typedef __attribute__((ext_vector_type(8))) unsigned short ushortx8;
typedef __attribute__((ext_vector_type(4))) unsigned short ushortx4;

__device__ __forceinline__ u16 f2bf(float f) {  // RNE
  unsigned int u = __builtin_bit_cast(unsigned int, f);
  unsigned int r = (u + 0x7FFFu + ((u >> 16) & 1u)) >> 16;
  return (u16)r;
}

// Raw hardware 2^x (R5/R6 hardware-verified: correct + cheap).
#if __has_builtin(__builtin_amdgcn_exp2f)
#define EXP2(x) __builtin_amdgcn_exp2f(x)
#else
#define EXP2(x) __expf((x) * 0.6931471805599453f)
#endif

// ---------------------------------------------------------------------------
// Cast Wq|Wk|Wv fp32 -> Wb bf16 [192][1024]. grid 192 x 256.
// ---------------------------------------------------------------------------
__global__ __launch_bounds__(256) void cast_w_kernel(
    const float* __restrict__ Wq, const float* __restrict__ Wk,
    const float* __restrict__ Wv, u16* __restrict__ Wb) {
  int i = blockIdx.x * 256 + threadIdx.x;  // float4 index, 49152 total
  const float* src = (i < 16384) ? Wq : ((i < 32768) ? Wk : Wv);
  int j = i & 16383;
  float4 v = ((const float4*)src)[j];
  ushortx4 o = {f2bf(v.x), f2bf(v.y), f2bf(v.z), f2bf(v.w)};
  *(ushortx4*)(Wb + (size_t)i * 4) = o;
}

// ---------------------------------------------------------------------------
// QKV projection v11 = R6's proj9 (64-row tiles, grid 256, W/wave = 96 KB,
// block W = 384 KB, chip W = 96 MB -- reverting R9's 192 MB regression) with
// two DEPTH fixes on the verified structure:
//  (a) W register ring depth 4 -> 8 (wf[8][3], refill s+8). R9 counters show
//      the k-loop is outstanding-bytes-limited on the W stream: depth-4 ring
//      = 192 B in flight/wave ~= 1.5 GB/s/wave (Little's law at ~300cy L2).
//      Depth 8 doubles it. VGPR ~180, still 1 block/CU (LDS-bound).
//  (b) staging unroll 4 -> 8: doubles outstanding x loads.
// Q pre-scaled by 0.125*log2(e) (verified R3..R9). grid 256 x 256.
// ---------------------------------------------------------------------------
__global__ __launch_bounds__(256) void proj9_kernel(
    const float* __restrict__ x, const u16* __restrict__ Wb,
    u16* __restrict__ Qb, u16* __restrict__ Kb, u16* __restrict__ Vt) {
  const int m0 = (int)blockIdx.x * 64;
  const int tid = threadIdx.x;
  const int wave = tid >> 6, lane = tid & 63;
  const int lq = lane & 15, quad = lane >> 4;

  __shared__ __align__(16) u16 xs[64 * 1024];  // 128 KB

  // ---- W ring preload, depth 8 (issued first; completes under staging) ----
  const u16* wp0 = Wb + (size_t)((wave * 3 + 0) * 16 + lq) * C_ + quad * 8;
  const u16* wp1 = Wb + (size_t)((wave * 3 + 1) * 16 + lq) * C_ + quad * 8;
  const u16* wp2 = Wb + (size_t)((wave * 3 + 2) * 16 + lq) * C_ + quad * 8;
  short8 wf[8][3];
#pragma unroll
  for (int d = 0; d < 8; ++d) {
    wf[d][0] = *(const short8*)(wp0 + d * 32);
    wf[d][1] = *(const short8*)(wp1 + d * 32);
    wf[d][2] = *(const short8*)(wp2 + d * 32);
  }

  // ---- stage x fp32->bf16 into swizzled LDS (deep pipeline, unroll 8) ----
#pragma unroll 8
  for (int i = 0; i < 32; ++i) {
    int g = i * 256 + tid;      // 16B-bf16 chunk id
    int row = g >> 7, c = g & 127;
    const float* src = x + (size_t)(m0 + row) * C_ + c * 8;
    float4 a = *(const float4*)(src);
    float4 b = *(const float4*)(src + 4);
    ushortx8 v = {f2bf(a.x), f2bf(a.y), f2bf(a.z), f2bf(a.w),
                  f2bf(b.x), f2bf(b.y), f2bf(b.z), f2bf(b.w)};
    *(ushortx8*)&xs[(row * 128 + (c ^ (row & 7))) * 8] = v;
  }
  __syncthreads();

  floatx4 acc[4][3];
#pragma unroll
  for (int rt = 0; rt < 4; ++rt)
#pragma unroll
    for (int j = 0; j < 3; ++j) acc[rt][j] = (floatx4){0.f, 0.f, 0.f, 0.f};

  // ---- k-loop: 32 steps of k=32; use slot s&7, then refill for s+8 ----
#pragma unroll
  for (int s = 0; s < 32; ++s) {
    short8 af[4];
#pragma unroll
    for (int rt = 0; rt < 4; ++rt) {
      int row = rt * 16 + lq;
      int c = (s * 4 + quad) ^ (lq & 7);
      af[rt] = *(const short8*)&xs[(row * 128 + c) * 8];
    }
    const int sl = s & 7;
#pragma unroll
    for (int j = 0; j < 3; ++j) {
      short8 bf = wf[sl][j];
#pragma unroll
      for (int rt = 0; rt < 4; ++rt)
        acc[rt][j] =
            __builtin_amdgcn_mfma_f32_16x16x32_bf16(af[rt], bf, acc[rt][j], 0, 0, 0);
    }
    if (s + 8 < 32) {  // refill the slot just consumed
      wf[sl][0] = *(const short8*)(wp0 + (s + 8) * 32);
      wf[sl][1] = *(const short8*)(wp1 + (s + 8) * 32);
      wf[sl][2] = *(const short8*)(wp2 + (s + 8) * 32);
    }
  }

  // ---- epilogue: acc -> sm (aliased over xs) -> coalesced stores ----
  __syncthreads();  // all waves done reading xs
  u16(*sm)[208] = (u16(*)[208])xs;
#pragma unroll
  for (int j = 0; j < 3; ++j) {
    const int gc = (wave * 3 + j) * 16;  // 16-col tile, never straddles
    // fold 64^-0.5 AND log2(e) into Q: 0.125 * 1.4426950408889634
    const float sc = (gc < 64) ? 0.18033688011112042f : 1.0f;
#pragma unroll
    for (int rt = 0; rt < 4; ++rt)
#pragma unroll
      for (int r = 0; r < 4; ++r)
        sm[rt * 16 + quad * 4 + r][gc + lq] = f2bf(acc[rt][j][r] * sc);
  }
  __syncthreads();

  // verified store block (R0..R6)
  const int row = tid >> 2, hseg = (tid & 3) * 16;
  {
    ushortx8 w0 = *(const ushortx8*)&sm[row][hseg];
    ushortx8 w1 = *(const ushortx8*)&sm[row][hseg + 8];
    u16* dq = Qb + (size_t)(m0 + row) * H_ + hseg;
    *(ushortx8*)dq = w0;
    *(ushortx8*)(dq + 8) = w1;
  }
  {
    ushortx8 w0 = *(const ushortx8*)&sm[row][64 + hseg];
    ushortx8 w1 = *(const ushortx8*)&sm[row][64 + hseg + 8];
    u16* dk = Kb + (size_t)(m0 + row) * H_ + hseg;
    *(ushortx8*)dk = w0;
    *(ushortx8*)(dk + 8) = w1;
  }
  {
    const int h = tid >> 2, tseg = (tid & 3) * 16;
    u16 tmp[16];
#pragma unroll
    for (int tt = 0; tt < 16; ++tt) tmp[tt] = sm[tseg + tt][128 + h];
    ushortx8 w0, w1;
#pragma unroll
    for (int tt = 0; tt < 8; ++tt) { w0[tt] = tmp[tt]; w1[tt] = tmp[8 + tt]; }
    const int bb = m0 >> 12, t0 = m0 & 4095;
    u16* dv = Vt + ((size_t)bb * H_ + h) * T_ + t0 + tseg;
    *(ushortx8*)dv = w0;
    *(ushortx8*)(dv + 8) = w1;
  }
}

// ---------------------------------------------------------------------------
// Flash attention: EXACT R6 core (measured best, attn 41.0us, absmax 0.031).
// Dual-buffer K/V staging, one barrier/chunk, no occupancy hint, EXP2
// builtin, trunc-pack P -> ps LDS (ushortx4), verified b128 pa read,
// wave-uniform mask hoist + tail skip, 2-shuffle lrow reduce. KS=8.
// grid (32, B*KS).
// ---------------------------------------------------------------------------
__global__ __launch_bounds__(256) void attn_kernel(
    const u16* __restrict__ Qb, const u16* __restrict__ Kb,
    const u16* __restrict__ Vt, float* __restrict__ Opart,
    float* __restrict__ lpart, int KS, int kslog) {
  const int tau = (int)gridDim.x - 1 - (int)blockIdx.x;  // LPT: heavy first
  const int q0 = tau * 128;
  const int b = (int)blockIdx.y >> kslog;
  const int s = (int)blockIdx.y & (KS - 1);
  const int tid = threadIdx.x;
  const int wave = tid >> 6, lane = tid & 63;
  const int lq = lane & 15, quad = lane >> 4;
  const int sw = lq & 7;

  __shared__ __align__(16) u16 ksh[2][64 * 64];
  __shared__ __align__(16) u16 vsh[2][64 * 64];
  __shared__ __align__(16) u16 ps[4][32 * 72];

  const int nch = 2 * tau + 2;  // 64-key chunks incl. diagonal
  const u16* Kb_b = Kb + (size_t)b * T_ * H_;
  const u16* Vt_b = Vt + (size_t)b * H_ * T_;

  short8 qa[2][2];
#pragma unroll
  for (int rt = 0; rt < 2; ++rt) {
    const u16* qrow =
        Qb + ((size_t)b * T_ + q0 + wave * 32 + rt * 16 + lq) * H_;
    qa[rt][0] = *(const short8*)(qrow + quad * 8);
    qa[rt][1] = *(const short8*)(qrow + 32 + quad * 8);
  }

  floatx4 o[2][4];
  float lrow[2] = {0.f, 0.f};
#pragma unroll
  for (int rt = 0; rt < 2; ++rt)
#pragma unroll
    for (int t = 0; t < 4; ++t) o[rt][t] = (floatx4){0.f, 0.f, 0.f, 0.f};

  const float nbias = -5.770780163555852f;  // -4 * log2(e)

  const int srow = tid >> 3;  // 0..31
  const int sseg = tid & 7;
  const int spos0 = (srow * 8 + (sseg ^ (srow & 7))) * 8;  // u16 index
  const int spos1 = spos0 + 2048;                          // row+32, same xor

  int4 kst0, kst1, vst0, vst1;
#define STAGE_LOAD(S0)                                                        \
  {                                                                           \
    kst0 = *(const int4*)(Kb_b + (size_t)((S0) + srow) * H_ + sseg * 8);      \
    kst1 = *(const int4*)(Kb_b + (size_t)((S0) + srow + 32) * H_ + sseg * 8); \
    vst0 = *(const int4*)(Vt_b + (size_t)srow * T_ + (S0) + sseg * 8);        \
    vst1 = *(const int4*)(Vt_b + (size_t)(srow + 32) * T_ + (S0) + sseg * 8); \
  }
#define STAGE_WRITE(BUF)                                                      \
  {                                                                           \
    *(int4*)&ksh[BUF][spos0] = kst0;                                          \
    *(int4*)&ksh[BUF][spos1] = kst1;                                          \
    *(int4*)&vsh[BUF][spos0] = vst0;                                          \
    *(int4*)&vsh[BUF][spos1] = vst1;                                          \
  }

  int ch = s, buf = 0;
  if (ch < nch) {
    STAGE_LOAD(ch * 64)
    STAGE_WRITE(0)
  }
  __syncthreads();

  if (ch < nch) {
    const int qmaxw = q0 + wave * 32 + 31;  // last q row this wave owns
    for (;;) {
      const bool have_next = (ch + KS < nch);
      if (have_next) { STAGE_LOAD((ch + KS) * 64) }
      const int s0 = ch * 64;

      if (s0 <= qmaxw) {  // wave-uniform: skip fully-masked tail chunk
        // ---- QK^T swapped: z[rt][t][r] = S[key=s0+t*16+quad*4+r][q=..+lq]
        floatx4 z[2][4];
#pragma unroll
        for (int t = 0; t < 4; ++t) {
          const int row8 = (t * 16 + lq) * 8;
          short8 kb0 = *(const short8*)&ksh[buf][(row8 + (quad ^ sw)) * 8];
          short8 kb1 = *(const short8*)&ksh[buf][(row8 + ((quad + 4) ^ sw)) * 8];
#pragma unroll
          for (int rt = 0; rt < 2; ++rt) {
            floatx4 zz = (floatx4){nbias, nbias, nbias, nbias};
            zz = __builtin_amdgcn_mfma_f32_16x16x32_bf16(kb0, qa[rt][0], zz, 0, 0, 0);
            zz = __builtin_amdgcn_mfma_f32_16x16x32_bf16(kb1, qa[rt][1], zz, 0, 0, 0);
            z[rt][t] = zz;
          }
        }

        // ---- softmax: p = 2^z; mask only diagonal chunks; packed store ----
#pragma unroll
        for (int rt = 0; rt < 2; ++rt) {
          const int qr = q0 + wave * 32 + rt * 16 + lq;
          const bool nm = (s0 + 63 > q0 + wave * 32 + rt * 16);  // wave-uniform
#pragma unroll
          for (int t = 0; t < 4; ++t) {
            float p0 = EXP2(z[rt][t][0]);
            float p1 = EXP2(z[rt][t][1]);
            float p2 = EXP2(z[rt][t][2]);
            float p3 = EXP2(z[rt][t][3]);
            if (nm) {
              const int k0 = s0 + t * 16 + quad * 4;
              p0 = (k0 + 0 > qr) ? 0.f : p0;
              p1 = (k0 + 1 > qr) ? 0.f : p1;
              p2 = (k0 + 2 > qr) ? 0.f : p2;
              p3 = (k0 + 3 > qr) ? 0.f : p3;
            }
            lrow[rt] += (p0 + p1) + (p2 + p3);
            // truncation-pack: bf16 = high half of fp32 bits (R6-verified)
            const unsigned int u0 = __builtin_bit_cast(unsigned int, p0);
            const unsigned int u1 = __builtin_bit_cast(unsigned int, p1);
            const unsigned int u2 = __builtin_bit_cast(unsigned int, p2);
            const unsigned int u3 = __builtin_bit_cast(unsigned int, p3);
            ushortx4 pk = {(u16)(u0 >> 16), (u16)(u1 >> 16), (u16)(u2 >> 16),
                           (u16)(u3 >> 16)};
            *(ushortx4*)&ps[wave][(rt * 16 + lq) * 72 + t * 16 + quad * 4] = pk;
          }
        }

        // ---- pa: verified b128 read (A-frag: row=q, k=key) ----
        short8 pa[2][2];
#pragma unroll
        for (int rt = 0; rt < 2; ++rt) {
          pa[rt][0] = *(const short8*)&ps[wave][(rt * 16 + lq) * 72 + quad * 8];
          pa[rt][1] =
              *(const short8*)&ps[wave][(rt * 16 + lq) * 72 + 32 + quad * 8];
        }

        // ---- PV from staged V^T ----
#pragma unroll
        for (int t = 0; t < 4; ++t) {
          const int row8 = (t * 16 + lq) * 8;
          short8 vb0 = *(const short8*)&vsh[buf][(row8 + (quad ^ sw)) * 8];
          short8 vb1 = *(const short8*)&vsh[buf][(row8 + ((quad + 4) ^ sw)) * 8];
#pragma unroll
          for (int rt = 0; rt < 2; ++rt) {
            o[rt][t] = __builtin_amdgcn_mfma_f32_16x16x32_bf16(pa[rt][0], vb0,
                                                               o[rt][t], 0, 0, 0);
            o[rt][t] = __builtin_amdgcn_mfma_f32_16x16x32_bf16(pa[rt][1], vb1,
                                                               o[rt][t], 0, 0, 0);
          }
        }
      }

      if (!have_next) break;
      STAGE_WRITE(buf ^ 1)
      __syncthreads();
      buf ^= 1;
      ch += KS;
    }
  }

  // lrow partials live per-quad: reduce across lane bits 4,5
#pragma unroll
  for (int rt = 0; rt < 2; ++rt) {
    lrow[rt] += __shfl_xor(lrow[rt], 16);
    lrow[rt] += __shfl_xor(lrow[rt], 32);
  }

  const size_t prow = (size_t)((b << kslog) + s) * T_ + q0 + wave * 32;
#pragma unroll
  for (int rt = 0; rt < 2; ++rt) {
#pragma unroll
    for (int t = 0; t < 4; ++t)
#pragma unroll
      for (int r = 0; r < 4; ++r)
        Opart[(prow + rt * 16 + quad * 4 + r) * H_ + t * 16 + lq] =
            o[rt][t][r];
    if (quad == 0) lpart[prow + rt * 16 + lq] = lrow[rt];
  }
}

// ---------------------------------------------------------------------------
// Combine: out[b][t][h] = Sum_s Opart / Sum_s lpart. grid 1024 x 256.
// ---------------------------------------------------------------------------
__global__ __launch_bounds__(256) void combine_kernel(
    const float* __restrict__ Opart, const float* __restrict__ lpart,
    float* __restrict__ out, int KS, int kslog) {
  int gid = blockIdx.x * 256 + threadIdx.x;  // 262144 float4 groups
  int b = gid >> 16;
  int rem = gid & 65535;
  int t = rem >> 4;
  int hs = (rem & 15) * 4;
  float sx = 0.f, sy = 0.f, sz = 0.f, sw = 0.f, ls = 0.f;
  for (int s = 0; s < KS; ++s) {
    size_t row = (size_t)((b << kslog) + s) * T_ + t;
    float4 v = *(const float4*)(Opart + row * H_ + hs);
    sx += v.x; sy += v.y; sz += v.z; sw += v.w;
    ls += lpart[row];
  }
  float inv = 1.f / ls;
  float4 o = make_float4(sx * inv, sy * inv, sz * inv, sw * inv);
  *(float4*)(out + ((size_t)b * T_ + t) * H_ + hs) = o;
}

extern "C" void kernel_launch(void* const* d_in, const int* in_sizes, int n_in,
                              void* d_out, int out_size, void* d_ws, size_t ws_size,
                              hipStream_t stream) {
  const float* x = (const float*)d_in[0];
  const float* Wq = (const float*)d_in[1];
  const float* Wk = (const float*)d_in[2];
  const float* Wv = (const float*)d_in[3];
  u16* Qb = (u16*)d_ws;                    // [16384][64] bf16, pre-scaled log2e/8
  u16* Kb = Qb + (size_t)NROW * H_;        // [16384][64] bf16
  u16* Vt = Kb + (size_t)NROW * H_;        // [4][64][4096] bf16 (transposed)
  u16* Wb = Vt + (size_t)NROW * H_;        // [192][1024] bf16
  const size_t base = (size_t)3 * NROW * H_ * 2 + 192 * 1024 * 2;  // 6.68 MB

  // split factor: largest of {8,4,2,1} whose partials fit in ws
  int KS = 8;
  while (KS > 1 &&
         base + (size_t)KS * ((size_t)B_ * T_ * H_ * 4 + (size_t)B_ * T_ * 4) >
             ws_size)
    KS >>= 1;
  int kslog = (KS == 8) ? 3 : (KS == 4) ? 2 : (KS == 2) ? 1 : 0;

  float* Opart = (float*)((char*)d_ws + base);          // [B*KS][T][64] fp32
  float* lpart = Opart + (size_t)KS * B_ * T_ * H_;     // [B*KS][T] fp32
  float* out = (float*)d_out;

  cast_w_kernel<<<dim3(192), 256, 0, stream>>>(Wq, Wk, Wv, Wb);
  proj9_kernel<<<dim3(256), 256, 0, stream>>>(x, Wb, Qb, Kb, Vt);
  attn_kernel<<<dim3(32, B_ * KS), 256, 0, stream>>>(Qb, Kb, Vt, Opart, lpart,
                                                     KS, kslog);
  combine_kernel<<<dim3(1024), 256, 0, stream>>>(Opart, lpart, out, KS, kslog);
}

// Round 11
// 150.381 us; speedup vs baseline: 1.1294x; 1.1294x over previous
//
#include <hip/hip_runtime.h>
#include <math.h>

#define B_ 4
#define T_ 4096
#define C_ 1024
#define H_ 64
#define NROW (B_ * T_)  // 16384

typedef unsigned short u16;
typedef __attribute__((ext_vector_type(8))) short short8;
typedef __attribute__((ext_vector_type(4))) float floatx4;
typedef __attribute__((ext_vector_type(8))) unsigned short ushortx8;
typedef __attribute__((ext_vector_type(4))) unsigned short ushortx4;

__device__ __forceinline__ u16 f2bf(float f) {  // RNE
  unsigned int u = __builtin_bit_cast(unsigned int, f);
  unsigned int r = (u + 0x7FFFu + ((u >> 16) & 1u)) >> 16;
  return (u16)r;
}

// Raw hardware 2^x (R5/R6 hardware-verified: correct + cheap).
#if __has_builtin(__builtin_amdgcn_exp2f)
#define EXP2(x) __builtin_amdgcn_exp2f(x)
#else
#define EXP2(x) __expf((x) * 0.6931471805599453f)
#endif

// ---------------------------------------------------------------------------
// Cast Wq|Wk|Wv fp32 -> Wb bf16 [192][1024]. grid 192 x 256.
// ---------------------------------------------------------------------------
__global__ __launch_bounds__(256) void cast_w_kernel(
    const float* __restrict__ Wq, const float* __restrict__ Wk,
    const float* __restrict__ Wv, u16* __restrict__ Wb) {
  int i = blockIdx.x * 256 + threadIdx.x;  // float4 index, 49152 total
  const float* src = (i < 16384) ? Wq : ((i < 32768) ? Wk : Wv);
  int j = i & 16383;
  float4 v = ((const float4*)src)[j];
  ushortx4 o = {f2bf(v.x), f2bf(v.y), f2bf(v.z), f2bf(v.w)};
  *(ushortx4*)(Wb + (size_t)i * 4) = o;
}

// ---------------------------------------------------------------------------
// QKV projection v9 -- EXACT R6 configuration (measured best: depth-4 W ring,
// unroll-4 staging, 64-row tiles, grid 256). R9 (32-row tiles: 2x W traffic)
// and R10 (depth-8 ring: +36 VGPR, no gain) both regressed. Q pre-scaled by
// 0.125*log2(e) (verified R3..R10).
// ---------------------------------------------------------------------------
__global__ __launch_bounds__(256) void proj9_kernel(
    const float* __restrict__ x, const u16* __restrict__ Wb,
    u16* __restrict__ Qb, u16* __restrict__ Kb, u16* __restrict__ Vt) {
  const int m0 = (int)blockIdx.x * 64;
  const int tid = threadIdx.x;
  const int wave = tid >> 6, lane = tid & 63;
  const int lq = lane & 15, quad = lane >> 4;

  __shared__ __align__(16) u16 xs[64 * 1024];  // 128 KB

  // ---- W ring preload (issued first; completes under x staging) ----
  const u16* wp0 = Wb + (size_t)((wave * 3 + 0) * 16 + lq) * C_ + quad * 8;
  const u16* wp1 = Wb + (size_t)((wave * 3 + 1) * 16 + lq) * C_ + quad * 8;
  const u16* wp2 = Wb + (size_t)((wave * 3 + 2) * 16 + lq) * C_ + quad * 8;
  short8 wf[4][3];
#pragma unroll
  for (int d = 0; d < 4; ++d) {
    wf[d][0] = *(const short8*)(wp0 + d * 32);
    wf[d][1] = *(const short8*)(wp1 + d * 32);
    wf[d][2] = *(const short8*)(wp2 + d * 32);
  }

  // ---- stage x fp32->bf16 into swizzled LDS (coalesced, deep pipeline) ----
#pragma unroll 4
  for (int i = 0; i < 32; ++i) {
    int g = i * 256 + tid;      // 16B-bf16 chunk id
    int row = g >> 7, c = g & 127;
    const float* src = x + (size_t)(m0 + row) * C_ + c * 8;
    float4 a = *(const float4*)(src);
    float4 b = *(const float4*)(src + 4);
    ushortx8 v = {f2bf(a.x), f2bf(a.y), f2bf(a.z), f2bf(a.w),
                  f2bf(b.x), f2bf(b.y), f2bf(b.z), f2bf(b.w)};
    *(ushortx8*)&xs[(row * 128 + (c ^ (row & 7))) * 8] = v;
  }
  __syncthreads();

  floatx4 acc[4][3];
#pragma unroll
  for (int rt = 0; rt < 4; ++rt)
#pragma unroll
    for (int j = 0; j < 3; ++j) acc[rt][j] = (floatx4){0.f, 0.f, 0.f, 0.f};

  // ---- k-loop: 32 steps of k=32; use slot s&3, then refill for s+4 ----
#pragma unroll
  for (int s = 0; s < 32; ++s) {
    short8 af[4];
#pragma unroll
    for (int rt = 0; rt < 4; ++rt) {
      int row = rt * 16 + lq;
      int c = (s * 4 + quad) ^ (lq & 7);
      af[rt] = *(const short8*)&xs[(row * 128 + c) * 8];
    }
    const int sl = s & 3;
#pragma unroll
    for (int j = 0; j < 3; ++j) {
      short8 bf = wf[sl][j];
#pragma unroll
      for (int rt = 0; rt < 4; ++rt)
        acc[rt][j] =
            __builtin_amdgcn_mfma_f32_16x16x32_bf16(af[rt], bf, acc[rt][j], 0, 0, 0);
    }
    if (s + 4 < 32) {  // refill the slot just consumed
      wf[sl][0] = *(const short8*)(wp0 + (s + 4) * 32);
      wf[sl][1] = *(const short8*)(wp1 + (s + 4) * 32);
      wf[sl][2] = *(const short8*)(wp2 + (s + 4) * 32);
    }
  }

  // ---- epilogue: acc -> sm (aliased over xs) -> coalesced stores ----
  __syncthreads();  // all waves done reading xs
  u16(*sm)[208] = (u16(*)[208])xs;
#pragma unroll
  for (int j = 0; j < 3; ++j) {
    const int gc = (wave * 3 + j) * 16;  // 16-col tile, never straddles
    // fold 64^-0.5 AND log2(e) into Q: 0.125 * 1.4426950408889634
    const float sc = (gc < 64) ? 0.18033688011112042f : 1.0f;
#pragma unroll
    for (int rt = 0; rt < 4; ++rt)
#pragma unroll
      for (int r = 0; r < 4; ++r)
        sm[rt * 16 + quad * 4 + r][gc + lq] = f2bf(acc[rt][j][r] * sc);
  }
  __syncthreads();

  // verified store block (R0..R6)
  const int row = tid >> 2, hseg = (tid & 3) * 16;
  {
    ushortx8 w0 = *(const ushortx8*)&sm[row][hseg];
    ushortx8 w1 = *(const ushortx8*)&sm[row][hseg + 8];
    u16* dq = Qb + (size_t)(m0 + row) * H_ + hseg;
    *(ushortx8*)dq = w0;
    *(ushortx8*)(dq + 8) = w1;
  }
  {
    ushortx8 w0 = *(const ushortx8*)&sm[row][64 + hseg];
    ushortx8 w1 = *(const ushortx8*)&sm[row][64 + hseg + 8];
    u16* dk = Kb + (size_t)(m0 + row) * H_ + hseg;
    *(ushortx8*)dk = w0;
    *(ushortx8*)(dk + 8) = w1;
  }
  {
    const int h = tid >> 2, tseg = (tid & 3) * 16;
    u16 tmp[16];
#pragma unroll
    for (int tt = 0; tt < 16; ++tt) tmp[tt] = sm[tseg + tt][128 + h];
    ushortx8 w0, w1;
#pragma unroll
    for (int tt = 0; tt < 8; ++tt) { w0[tt] = tmp[tt]; w1[tt] = tmp[8 + tt]; }
    const int bb = m0 >> 12, t0 = m0 & 4095;
    u16* dv = Vt + ((size_t)bb * H_ + h) * T_ + t0 + tseg;
    *(ushortx8*)dv = w0;
    *(ushortx8*)(dv + 8) = w1;
  }
}

// ---------------------------------------------------------------------------
// Flash attention: EXACT R6 core (measured best, attn 41.0us, absmax 0.031).
// Dual-buffer K/V staging, one barrier/chunk, no occupancy hint, EXP2
// builtin, trunc-pack P -> ps LDS (ushortx4), verified b128 pa read,
// wave-uniform mask hoist + tail skip, 2-shuffle lrow reduce.
// R11 change is in the LAUNCHER only: KS=4 (R7->R8 A/B proved Opart traffic
// is a real linear cost while chain length is not the controlling factor).
// grid (32, B*KS).
// ---------------------------------------------------------------------------
__global__ __launch_bounds__(256) void attn_kernel(
    const u16* __restrict__ Qb, const u16* __restrict__ Kb,
    const u16* __restrict__ Vt, float* __restrict__ Opart,
    float* __restrict__ lpart, int KS, int kslog) {
  const int tau = (int)gridDim.x - 1 - (int)blockIdx.x;  // LPT: heavy first
  const int q0 = tau * 128;
  const int b = (int)blockIdx.y >> kslog;
  const int s = (int)blockIdx.y & (KS - 1);
  const int tid = threadIdx.x;
  const int wave = tid >> 6, lane = tid & 63;
  const int lq = lane & 15, quad = lane >> 4;
  const int sw = lq & 7;

  __shared__ __align__(16) u16 ksh[2][64 * 64];
  __shared__ __align__(16) u16 vsh[2][64 * 64];
  __shared__ __align__(16) u16 ps[4][32 * 72];

  const int nch = 2 * tau + 2;  // 64-key chunks incl. diagonal
  const u16* Kb_b = Kb + (size_t)b * T_ * H_;
  const u16* Vt_b = Vt + (size_t)b * H_ * T_;

  short8 qa[2][2];
#pragma unroll
  for (int rt = 0; rt < 2; ++rt) {
    const u16* qrow =
        Qb + ((size_t)b * T_ + q0 + wave * 32 + rt * 16 + lq) * H_;
    qa[rt][0] = *(const short8*)(qrow + quad * 8);
    qa[rt][1] = *(const short8*)(qrow + 32 + quad * 8);
  }

  floatx4 o[2][4];
  float lrow[2] = {0.f, 0.f};
#pragma unroll
  for (int rt = 0; rt < 2; ++rt)
#pragma unroll
    for (int t = 0; t < 4; ++t) o[rt][t] = (floatx4){0.f, 0.f, 0.f, 0.f};

  const float nbias = -5.770780163555852f;  // -4 * log2(e)

  const int srow = tid >> 3;  // 0..31
  const int sseg = tid & 7;
  const int spos0 = (srow * 8 + (sseg ^ (srow & 7))) * 8;  // u16 index
  const int spos1 = spos0 + 2048;                          // row+32, same xor

  int4 kst0, kst1, vst0, vst1;
#define STAGE_LOAD(S0)                                                        \
  {                                                                           \
    kst0 = *(const int4*)(Kb_b + (size_t)((S0) + srow) * H_ + sseg * 8);      \
    kst1 = *(const int4*)(Kb_b + (size_t)((S0) + srow + 32) * H_ + sseg * 8); \
    vst0 = *(const int4*)(Vt_b + (size_t)srow * T_ + (S0) + sseg * 8);        \
    vst1 = *(const int4*)(Vt_b + (size_t)(srow + 32) * T_ + (S0) + sseg * 8); \
  }
#define STAGE_WRITE(BUF)                                                      \
  {                                                                           \
    *(int4*)&ksh[BUF][spos0] = kst0;                                          \
    *(int4*)&ksh[BUF][spos1] = kst1;                                          \
    *(int4*)&vsh[BUF][spos0] = vst0;                                          \
    *(int4*)&vsh[BUF][spos1] = vst1;                                          \
  }

  int ch = s, buf = 0;
  if (ch < nch) {
    STAGE_LOAD(ch * 64)
    STAGE_WRITE(0)
  }
  __syncthreads();

  if (ch < nch) {
    const int qmaxw = q0 + wave * 32 + 31;  // last q row this wave owns
    for (;;) {
      const bool have_next = (ch + KS < nch);
      if (have_next) { STAGE_LOAD((ch + KS) * 64) }
      const int s0 = ch * 64;

      if (s0 <= qmaxw) {  // wave-uniform: skip fully-masked tail chunk
        // ---- QK^T swapped: z[rt][t][r] = S[key=s0+t*16+quad*4+r][q=..+lq]
        floatx4 z[2][4];
#pragma unroll
        for (int t = 0; t < 4; ++t) {
          const int row8 = (t * 16 + lq) * 8;
          short8 kb0 = *(const short8*)&ksh[buf][(row8 + (quad ^ sw)) * 8];
          short8 kb1 = *(const short8*)&ksh[buf][(row8 + ((quad + 4) ^ sw)) * 8];
#pragma unroll
          for (int rt = 0; rt < 2; ++rt) {
            floatx4 zz = (floatx4){nbias, nbias, nbias, nbias};
            zz = __builtin_amdgcn_mfma_f32_16x16x32_bf16(kb0, qa[rt][0], zz, 0, 0, 0);
            zz = __builtin_amdgcn_mfma_f32_16x16x32_bf16(kb1, qa[rt][1], zz, 0, 0, 0);
            z[rt][t] = zz;
          }
        }

        // ---- softmax: p = 2^z; mask only diagonal chunks; packed store ----
#pragma unroll
        for (int rt = 0; rt < 2; ++rt) {
          const int qr = q0 + wave * 32 + rt * 16 + lq;
          const bool nm = (s0 + 63 > q0 + wave * 32 + rt * 16);  // wave-uniform
#pragma unroll
          for (int t = 0; t < 4; ++t) {
            float p0 = EXP2(z[rt][t][0]);
            float p1 = EXP2(z[rt][t][1]);
            float p2 = EXP2(z[rt][t][2]);
            float p3 = EXP2(z[rt][t][3]);
            if (nm) {
              const int k0 = s0 + t * 16 + quad * 4;
              p0 = (k0 + 0 > qr) ? 0.f : p0;
              p1 = (k0 + 1 > qr) ? 0.f : p1;
              p2 = (k0 + 2 > qr) ? 0.f : p2;
              p3 = (k0 + 3 > qr) ? 0.f : p3;
            }
            lrow[rt] += (p0 + p1) + (p2 + p3);
            // truncation-pack: bf16 = high half of fp32 bits (R6-verified)
            const unsigned int u0 = __builtin_bit_cast(unsigned int, p0);
            const unsigned int u1 = __builtin_bit_cast(unsigned int, p1);
            const unsigned int u2 = __builtin_bit_cast(unsigned int, p2);
            const unsigned int u3 = __builtin_bit_cast(unsigned int, p3);
            ushortx4 pk = {(u16)(u0 >> 16), (u16)(u1 >> 16), (u16)(u2 >> 16),
                           (u16)(u3 >> 16)};
            *(ushortx4*)&ps[wave][(rt * 16 + lq) * 72 + t * 16 + quad * 4] = pk;
          }
        }

        // ---- pa: verified b128 read (A-frag: row=q, k=key) ----
        short8 pa[2][2];
#pragma unroll
        for (int rt = 0; rt < 2; ++rt) {
          pa[rt][0] = *(const short8*)&ps[wave][(rt * 16 + lq) * 72 + quad * 8];
          pa[rt][1] =
              *(const short8*)&ps[wave][(rt * 16 + lq) * 72 + 32 + quad * 8];
        }

        // ---- PV from staged V^T ----
#pragma unroll
        for (int t = 0; t < 4; ++t) {
          const int row8 = (t * 16 + lq) * 8;
          short8 vb0 = *(const short8*)&vsh[buf][(row8 + (quad ^ sw)) * 8];
          short8 vb1 = *(const short8*)&vsh[buf][(row8 + ((quad + 4) ^ sw)) * 8];
#pragma unroll
          for (int rt = 0; rt < 2; ++rt) {
            o[rt][t] = __builtin_amdgcn_mfma_f32_16x16x32_bf16(pa[rt][0], vb0,
                                                               o[rt][t], 0, 0, 0);
            o[rt][t] = __builtin_amdgcn_mfma_f32_16x16x32_bf16(pa[rt][1], vb1,
                                                               o[rt][t], 0, 0, 0);
          }
        }
      }

      if (!have_next) break;
      STAGE_WRITE(buf ^ 1)
      __syncthreads();
      buf ^= 1;
      ch += KS;
    }
  }

  // lrow partials live per-quad: reduce across lane bits 4,5
#pragma unroll
  for (int rt = 0; rt < 2; ++rt) {
    lrow[rt] += __shfl_xor(lrow[rt], 16);
    lrow[rt] += __shfl_xor(lrow[rt], 32);
  }

  const size_t prow = (size_t)((b << kslog) + s) * T_ + q0 + wave * 32;
#pragma unroll
  for (int rt = 0; rt < 2; ++rt) {
#pragma unroll
    for (int t = 0; t < 4; ++t)
#pragma unroll
      for (int r = 0; r < 4; ++r)
        Opart[(prow + rt * 16 + quad * 4 + r) * H_ + t * 16 + lq] =
            o[rt][t][r];
    if (quad == 0) lpart[prow + rt * 16 + lq] = lrow[rt];
  }
}

// ---------------------------------------------------------------------------
// Combine: out[b][t][h] = Sum_s Opart / Sum_s lpart. grid 1024 x 256.
// ---------------------------------------------------------------------------
__global__ __launch_bounds__(256) void combine_kernel(
    const float* __restrict__ Opart, const float* __restrict__ lpart,
    float* __restrict__ out, int KS, int kslog) {
  int gid = blockIdx.x * 256 + threadIdx.x;  // 262144 float4 groups
  int b = gid >> 16;
  int rem = gid & 65535;
  int t = rem >> 4;
  int hs = (rem & 15) * 4;
  float sx = 0.f, sy = 0.f, sz = 0.f, sw = 0.f, ls = 0.f;
  for (int s = 0; s < KS; ++s) {
    size_t row = (size_t)((b << kslog) + s) * T_ + t;
    float4 v = *(const float4*)(Opart + row * H_ + hs);
    sx += v.x; sy += v.y; sz += v.z; sw += v.w;
    ls += lpart[row];
  }
  float inv = 1.f / ls;
  float4 o = make_float4(sx * inv, sy * inv, sz * inv, sw * inv);
  *(float4*)(out + ((size_t)b * T_ + t) * H_ + hs) = o;
}

extern "C" void kernel_launch(void* const* d_in, const int* in_sizes, int n_in,
                              void* d_out, int out_size, void* d_ws, size_t ws_size,
                              hipStream_t stream) {
  const float* x = (const float*)d_in[0];
  const float* Wq = (const float*)d_in[1];
  const float* Wk = (const float*)d_in[2];
  const float* Wv = (const float*)d_in[3];
  u16* Qb = (u16*)d_ws;                    // [16384][64] bf16, pre-scaled log2e/8
  u16* Kb = Qb + (size_t)NROW * H_;        // [16384][64] bf16
  u16* Vt = Kb + (size_t)NROW * H_;        // [4][64][4096] bf16 (transposed)
  u16* Wb = Vt + (size_t)NROW * H_;        // [192][1024] bf16
  const size_t base = (size_t)3 * NROW * H_ * 2 + 192 * 1024 * 2;  // 6.68 MB

  // split factor: KS=4 (R11 A/B -- halves Opart/lpart traffic vs KS=8;
  // R7->R8 showed chain length is not the controlling cost)
  int KS = 4;
  while (KS > 1 &&
         base + (size_t)KS * ((size_t)B_ * T_ * H_ * 4 + (size_t)B_ * T_ * 4) >
             ws_size)
    KS >>= 1;
  int kslog = (KS == 4) ? 2 : (KS == 2) ? 1 : 0;

  float* Opart = (float*)((char*)d_ws + base);          // [B*KS][T][64] fp32
  float* lpart = Opart + (size_t)KS * B_ * T_ * H_;     // [B*KS][T] fp32
  float* out = (float*)d_out;

  cast_w_kernel<<<dim3(192), 256, 0, stream>>>(Wq, Wk, Wv, Wb);
  proj9_kernel<<<dim3(256), 256, 0, stream>>>(x, Wb, Qb, Kb, Vt);
  attn_kernel<<<dim3(32, B_ * KS), 256, 0, stream>>>(Qb, Kb, Vt, Opart, lpart,
                                                     KS, kslog);
  combine_kernel<<<dim3(1024), 256, 0, stream>>>(Opart, lpart, out, KS, kslog);
}

// Round 13
// 146.770 us; speedup vs baseline: 1.1572x; 1.0246x over previous
//
#include <hip/hip_runtime.h>
#include <math.h>

#define B_ 4
#define T_ 4096
#define C_ 1024
#define H_ 64
#define NROW (B_ * T_)  // 16384

typedef unsigned short u16;
typedef __attribute__((ext_vector_type(8))) short short8;
typedef __attribute__((ext_vector_type(4))) float floatx4;
typedef __attribute__((ext_vector_type(8))) unsigned short ushortx8;
typedef __attribute__((ext_vector_type(4))) unsigned short ushortx4;

// address-space-qualified pointer types for global_load_lds
typedef const __attribute__((address_space(1))) void* gasp;
typedef __attribute__((address_space(3))) void* lasp;
#define GLOAD_LDS16(GP, LP) \
  __builtin_amdgcn_global_load_lds((gasp)(GP), (lasp)(LP), 16, 0, 0)

__device__ __forceinline__ u16 f2bf(float f) {  // RNE
  unsigned int u = __builtin_bit_cast(unsigned int, f);
  unsigned int r = (u + 0x7FFFu + ((u >> 16) & 1u)) >> 16;
  return (u16)r;
}

// Raw hardware 2^x (R5/R6 hardware-verified: correct + cheap).
#if __has_builtin(__builtin_amdgcn_exp2f)
#define EXP2(x) __builtin_amdgcn_exp2f(x)
#else
#define EXP2(x) __expf((x) * 0.6931471805599453f)
#endif

// ---------------------------------------------------------------------------
// Cast Wq|Wk|Wv fp32 -> Wb bf16 [192][1024]. grid 192 x 256.
// ---------------------------------------------------------------------------
__global__ __launch_bounds__(256) void cast_w_kernel(
    const float* __restrict__ Wq, const float* __restrict__ Wk,
    const float* __restrict__ Wv, u16* __restrict__ Wb) {
  int i = blockIdx.x * 256 + threadIdx.x;  // float4 index, 49152 total
  const float* src = (i < 16384) ? Wq : ((i < 32768) ? Wk : Wv);
  int j = i & 16383;
  float4 v = ((const float4*)src)[j];
  ushortx4 o = {f2bf(v.x), f2bf(v.y), f2bf(v.z), f2bf(v.w)};
  *(ushortx4*)(Wb + (size_t)i * 4) = o;
}

// ---------------------------------------------------------------------------
// QKV projection v9 -- EXACT R6 configuration (measured best: depth-4 W ring,
// unroll-4 staging, 64-row tiles, grid 256). R9 (32-row tiles: 2x W traffic)
// and R10 (depth-8 ring: +36 VGPR, no gain) both regressed. Q pre-scaled by
// 0.125*log2(e) (verified R3..R11).
// ---------------------------------------------------------------------------
__global__ __launch_bounds__(256) void proj9_kernel(
    const float* __restrict__ x, const u16* __restrict__ Wb,
    u16* __restrict__ Qb, u16* __restrict__ Kb, u16* __restrict__ Vt) {
  const int m0 = (int)blockIdx.x * 64;
  const int tid = threadIdx.x;
  const int wave = tid >> 6, lane = tid & 63;
  const int lq = lane & 15, quad = lane >> 4;

  __shared__ __align__(16) u16 xs[64 * 1024];  // 128 KB

  // ---- W ring preload (issued first; completes under x staging) ----
  const u16* wp0 = Wb + (size_t)((wave * 3 + 0) * 16 + lq) * C_ + quad * 8;
  const u16* wp1 = Wb + (size_t)((wave * 3 + 1) * 16 + lq) * C_ + quad * 8;
  const u16* wp2 = Wb + (size_t)((wave * 3 + 2) * 16 + lq) * C_ + quad * 8;
  short8 wf[4][3];
#pragma unroll
  for (int d = 0; d < 4; ++d) {
    wf[d][0] = *(const short8*)(wp0 + d * 32);
    wf[d][1] = *(const short8*)(wp1 + d * 32);
    wf[d][2] = *(const short8*)(wp2 + d * 32);
  }

  // ---- stage x fp32->bf16 into swizzled LDS (coalesced, deep pipeline) ----
#pragma unroll 4
  for (int i = 0; i < 32; ++i) {
    int g = i * 256 + tid;      // 16B-bf16 chunk id
    int row = g >> 7, c = g & 127;
    const float* src = x + (size_t)(m0 + row) * C_ + c * 8;
    float4 a = *(const float4*)(src);
    float4 b = *(const float4*)(src + 4);
    ushortx8 v = {f2bf(a.x), f2bf(a.y), f2bf(a.z), f2bf(a.w),
                  f2bf(b.x), f2bf(b.y), f2bf(b.z), f2bf(b.w)};
    *(ushortx8*)&xs[(row * 128 + (c ^ (row & 7))) * 8] = v;
  }
  __syncthreads();

  floatx4 acc[4][3];
#pragma unroll
  for (int rt = 0; rt < 4; ++rt)
#pragma unroll
    for (int j = 0; j < 3; ++j) acc[rt][j] = (floatx4){0.f, 0.f, 0.f, 0.f};

  // ---- k-loop: 32 steps of k=32; use slot s&3, then refill for s+4 ----
#pragma unroll
  for (int s = 0; s < 32; ++s) {
    short8 af[4];
#pragma unroll
    for (int rt = 0; rt < 4; ++rt) {
      int row = rt * 16 + lq;
      int c = (s * 4 + quad) ^ (lq & 7);
      af[rt] = *(const short8*)&xs[(row * 128 + c) * 8];
    }
    const int sl = s & 3;
#pragma unroll
    for (int j = 0; j < 3; ++j) {
      short8 bf = wf[sl][j];
#pragma unroll
      for (int rt = 0; rt < 4; ++rt)
        acc[rt][j] =
            __builtin_amdgcn_mfma_f32_16x16x32_bf16(af[rt], bf, acc[rt][j], 0, 0, 0);
    }
    if (s + 4 < 32) {  // refill the slot just consumed
      wf[sl][0] = *(const short8*)(wp0 + (s + 4) * 32);
      wf[sl][1] = *(const short8*)(wp1 + (s + 4) * 32);
      wf[sl][2] = *(const short8*)(wp2 + (s + 4) * 32);
    }
  }

  // ---- epilogue: acc -> sm (aliased over xs) -> coalesced stores ----
  __syncthreads();  // all waves done reading xs
  u16(*sm)[208] = (u16(*)[208])xs;
#pragma unroll
  for (int j = 0; j < 3; ++j) {
    const int gc = (wave * 3 + j) * 16;  // 16-col tile, never straddles
    // fold 64^-0.5 AND log2(e) into Q: 0.125 * 1.4426950408889634
    const float sc = (gc < 64) ? 0.18033688011112042f : 1.0f;
#pragma unroll
    for (int rt = 0; rt < 4; ++rt)
#pragma unroll
      for (int r = 0; r < 4; ++r)
        sm[rt * 16 + quad * 4 + r][gc + lq] = f2bf(acc[rt][j][r] * sc);
  }
  __syncthreads();

  // verified store block (R0..R6)
  const int row = tid >> 2, hseg = (tid & 3) * 16;
  {
    ushortx8 w0 = *(const ushortx8*)&sm[row][hseg];
    ushortx8 w1 = *(const ushortx8*)&sm[row][hseg + 8];
    u16* dq = Qb + (size_t)(m0 + row) * H_ + hseg;
    *(ushortx8*)dq = w0;
    *(ushortx8*)(dq + 8) = w1;
  }
  {
    ushortx8 w0 = *(const ushortx8*)&sm[row][64 + hseg];
    ushortx8 w1 = *(const ushortx8*)&sm[row][64 + hseg + 8];
    u16* dk = Kb + (size_t)(m0 + row) * H_ + hseg;
    *(ushortx8*)dk = w0;
    *(ushortx8*)(dk + 8) = w1;
  }
  {
    const int h = tid >> 2, tseg = (tid & 3) * 16;
    u16 tmp[16];
#pragma unroll
    for (int tt = 0; tt < 16; ++tt) tmp[tt] = sm[tseg + tt][128 + h];
    ushortx8 w0, w1;
#pragma unroll
    for (int tt = 0; tt < 8; ++tt) { w0[tt] = tmp[tt]; w1[tt] = tmp[8 + tt]; }
    const int bb = m0 >> 12, t0 = m0 & 4095;
    u16* dv = Vt + ((size_t)bb * H_ + h) * T_ + t0 + tseg;
    *(ushortx8*)dv = w0;
    *(ushortx8*)(dv + 8) = w1;
  }
}

// ---------------------------------------------------------------------------
// Flash attention v9 = R11 core (R6-verified compute, KS=4) with the K/V
// staging switched from reg-round-trip (global->VGPR->swizzled LDS scatter)
// to DIRECT global_load_lds DMA (m173 pattern): LDS dest stays LINEAR
// (wave-uniform base + lane*16); the XOR swizzle moves to the per-lane
// GLOBAL source address. Inverse mapping: LDS 16B-chunk c holds
// K-row (c>>3), segment (c&7)^((c>>3)&7) -- readers byte-identical to the
// verified layout. Removes 16 staged VGPRs + the STAGE_WRITE phase;
// __syncthreads() drains vmcnt before s_barrier (compiler-guaranteed), so
// the one-barrier-per-chunk dual-buffer dependence argument is unchanged.
// grid (32, B*KS).
// ---------------------------------------------------------------------------
__global__ __launch_bounds__(256) void attn_kernel(
    const u16* __restrict__ Qb, const u16* __restrict__ Kb,
    const u16* __restrict__ Vt, float* __restrict__ Opart,
    float* __restrict__ lpart, int KS, int kslog) {
  const int tau = (int)gridDim.x - 1 - (int)blockIdx.x;  // LPT: heavy first
  const int q0 = tau * 128;
  const int b = (int)blockIdx.y >> kslog;
  const int s = (int)blockIdx.y & (KS - 1);
  const int tid = threadIdx.x;
  const int wave = tid >> 6, lane = tid & 63;
  const int lq = lane & 15, quad = lane >> 4;
  const int sw = lq & 7;

  __shared__ __align__(16) u16 ksh[2][64 * 64];
  __shared__ __align__(16) u16 vsh[2][64 * 64];
  __shared__ __align__(16) u16 ps[4][32 * 72];

  const int nch = 2 * tau + 2;  // 64-key chunks incl. diagonal
  const u16* Kb_b = Kb + (size_t)b * T_ * H_;
  const u16* Vt_b = Vt + (size_t)b * H_ * T_;

  short8 qa[2][2];
#pragma unroll
  for (int rt = 0; rt < 2; ++rt) {
    const u16* qrow =
        Qb + ((size_t)b * T_ + q0 + wave * 32 + rt * 16 + lq) * H_;
    qa[rt][0] = *(const short8*)(qrow + quad * 8);
    qa[rt][1] = *(const short8*)(qrow + 32 + quad * 8);
  }

  floatx4 o[2][4];
  float lrow[2] = {0.f, 0.f};
#pragma unroll
  for (int rt = 0; rt < 2; ++rt)
#pragma unroll
    for (int t = 0; t < 4; ++t) o[rt][t] = (floatx4){0.f, 0.f, 0.f, 0.f};

  const float nbias = -5.770780163555852f;  // -4 * log2(e)

  // DMA source mapping (inverse of the verified XOR swizzle):
  // inst i (i=0,1) of each wave covers LDS chunks c = i*256 + tid.
  const int c0 = tid, c1 = 256 + tid;
  const int r0 = c0 >> 3, sg0 = (c0 & 7) ^ (r0 & 7);
  const int r1 = c1 >> 3, sg1 = (c1 & 7) ^ (r1 & 7);

#define STAGE_DMA(BUF, S0)                                                   \
  {                                                                          \
    GLOAD_LDS16(Kb_b + (size_t)((S0) + r0) * H_ + sg0 * 8,                   \
                &ksh[BUF][(wave * 64) * 8]);                                 \
    GLOAD_LDS16(Kb_b + (size_t)((S0) + r1) * H_ + sg1 * 8,                   \
                &ksh[BUF][(256 + wave * 64) * 8]);                           \
    GLOAD_LDS16(Vt_b + (size_t)r0 * T_ + (S0) + sg0 * 8,                     \
                &vsh[BUF][(wave * 64) * 8]);                                 \
    GLOAD_LDS16(Vt_b + (size_t)r1 * T_ + (S0) + sg1 * 8,                     \
                &vsh[BUF][(256 + wave * 64) * 8]);                           \
  }

  int ch = s, buf = 0;
  if (ch < nch) { STAGE_DMA(0, ch * 64) }
  __syncthreads();  // drains DMA vmcnt before barrier (compiler-inserted)

  if (ch < nch) {
    const int qmaxw = q0 + wave * 32 + 31;  // last q row this wave owns
    for (;;) {
      const bool have_next = (ch + KS < nch);
      if (have_next) { STAGE_DMA(buf ^ 1, (ch + KS) * 64) }  // async DMA
      const int s0 = ch * 64;

      if (s0 <= qmaxw) {  // wave-uniform: skip fully-masked tail chunk
        // ---- QK^T swapped: z[rt][t][r] = S[key=s0+t*16+quad*4+r][q=..+lq]
        floatx4 z[2][4];
#pragma unroll
        for (int t = 0; t < 4; ++t) {
          const int row8 = (t * 16 + lq) * 8;
          short8 kb0 = *(const short8*)&ksh[buf][(row8 + (quad ^ sw)) * 8];
          short8 kb1 = *(const short8*)&ksh[buf][(row8 + ((quad + 4) ^ sw)) * 8];
#pragma unroll
          for (int rt = 0; rt < 2; ++rt) {
            floatx4 zz = (floatx4){nbias, nbias, nbias, nbias};
            zz = __builtin_amdgcn_mfma_f32_16x16x32_bf16(kb0, qa[rt][0], zz, 0, 0, 0);
            zz = __builtin_amdgcn_mfma_f32_16x16x32_bf16(kb1, qa[rt][1], zz, 0, 0, 0);
            z[rt][t] = zz;
          }
        }

        // ---- softmax: p = 2^z; mask only diagonal chunks; packed store ----
#pragma unroll
        for (int rt = 0; rt < 2; ++rt) {
          const int qr = q0 + wave * 32 + rt * 16 + lq;
          const bool nm = (s0 + 63 > q0 + wave * 32 + rt * 16);  // wave-uniform
#pragma unroll
          for (int t = 0; t < 4; ++t) {
            float p0 = EXP2(z[rt][t][0]);
            float p1 = EXP2(z[rt][t][1]);
            float p2 = EXP2(z[rt][t][2]);
            float p3 = EXP2(z[rt][t][3]);
            if (nm) {
              const int k0 = s0 + t * 16 + quad * 4;
              p0 = (k0 + 0 > qr) ? 0.f : p0;
              p1 = (k0 + 1 > qr) ? 0.f : p1;
              p2 = (k0 + 2 > qr) ? 0.f : p2;
              p3 = (k0 + 3 > qr) ? 0.f : p3;
            }
            lrow[rt] += (p0 + p1) + (p2 + p3);
            // truncation-pack: bf16 = high half of fp32 bits (R6-verified)
            const unsigned int u0 = __builtin_bit_cast(unsigned int, p0);
            const unsigned int u1 = __builtin_bit_cast(unsigned int, p1);
            const unsigned int u2 = __builtin_bit_cast(unsigned int, p2);
            const unsigned int u3 = __builtin_bit_cast(unsigned int, p3);
            ushortx4 pk = {(u16)(u0 >> 16), (u16)(u1 >> 16), (u16)(u2 >> 16),
                           (u16)(u3 >> 16)};
            *(ushortx4*)&ps[wave][(rt * 16 + lq) * 72 + t * 16 + quad * 4] = pk;
          }
        }

        // ---- pa: verified b128 read (A-frag: row=q, k=key) ----
        short8 pa[2][2];
#pragma unroll
        for (int rt = 0; rt < 2; ++rt) {
          pa[rt][0] = *(const short8*)&ps[wave][(rt * 16 + lq) * 72 + quad * 8];
          pa[rt][1] =
              *(const short8*)&ps[wave][(rt * 16 + lq) * 72 + 32 + quad * 8];
        }

        // ---- PV from staged V^T ----
#pragma unroll
        for (int t = 0; t < 4; ++t) {
          const int row8 = (t * 16 + lq) * 8;
          short8 vb0 = *(const short8*)&vsh[buf][(row8 + (quad ^ sw)) * 8];
          short8 vb1 = *(const short8*)&vsh[buf][(row8 + ((quad + 4) ^ sw)) * 8];
#pragma unroll
          for (int rt = 0; rt < 2; ++rt) {
            o[rt][t] = __builtin_amdgcn_mfma_f32_16x16x32_bf16(pa[rt][0], vb0,
                                                               o[rt][t], 0, 0, 0);
            o[rt][t] = __builtin_amdgcn_mfma_f32_16x16x32_bf16(pa[rt][1], vb1,
                                                               o[rt][t], 0, 0, 0);
          }
        }
      }

      if (!have_next) break;
      __syncthreads();  // drains next-buf DMA (vmcnt) + all reads of buf
      buf ^= 1;
      ch += KS;
    }
  }

  // lrow partials live per-quad: reduce across lane bits 4,5
#pragma unroll
  for (int rt = 0; rt < 2; ++rt) {
    lrow[rt] += __shfl_xor(lrow[rt], 16);
    lrow[rt] += __shfl_xor(lrow[rt], 32);
  }

  const size_t prow = (size_t)((b << kslog) + s) * T_ + q0 + wave * 32;
#pragma unroll
  for (int rt = 0; rt < 2; ++rt) {
#pragma unroll
    for (int t = 0; t < 4; ++t)
#pragma unroll
      for (int r = 0; r < 4; ++r)
        Opart[(prow + rt * 16 + quad * 4 + r) * H_ + t * 16 + lq] =
            o[rt][t][r];
    if (quad == 0) lpart[prow + rt * 16 + lq] = lrow[rt];
  }
}

// ---------------------------------------------------------------------------
// Combine: out[b][t][h] = Sum_s Opart / Sum_s lpart. grid 1024 x 256.
// ---------------------------------------------------------------------------
__global__ __launch_bounds__(256) void combine_kernel(
    const float* __restrict__ Opart, const float* __restrict__ lpart,
    float* __restrict__ out, int KS, int kslog) {
  int gid = blockIdx.x * 256 + threadIdx.x;  // 262144 float4 groups
  int b = gid >> 16;
  int rem = gid & 65535;
  int t = rem >> 4;
  int hs = (rem & 15) * 4;
  float sx = 0.f, sy = 0.f, sz = 0.f, sw = 0.f, ls = 0.f;
  for (int s = 0; s < KS; ++s) {
    size_t row = (size_t)((b << kslog) + s) * T_ + t;
    float4 v = *(const float4*)(Opart + row * H_ + hs);
    sx += v.x; sy += v.y; sz += v.z; sw += v.w;
    ls += lpart[row];
  }
  float inv = 1.f / ls;
  float4 o = make_float4(sx * inv, sy * inv, sz * inv, sw * inv);
  *(float4*)(out + ((size_t)b * T_ + t) * H_ + hs) = o;
}

extern "C" void kernel_launch(void* const* d_in, const int* in_sizes, int n_in,
                              void* d_out, int out_size, void* d_ws, size_t ws_size,
                              hipStream_t stream) {
  const float* x = (const float*)d_in[0];
  const float* Wq = (const float*)d_in[1];
  const float* Wk = (const float*)d_in[2];
  const float* Wv = (const float*)d_in[3];
  u16* Qb = (u16*)d_ws;                    // [16384][64] bf16, pre-scaled log2e/8
  u16* Kb = Qb + (size_t)NROW * H_;        // [16384][64] bf16
  u16* Vt = Kb + (size_t)NROW * H_;        // [4][64][4096] bf16 (transposed)
  u16* Wb = Vt + (size_t)NROW * H_;        // [192][1024] bf16
  const size_t base = (size_t)3 * NROW * H_ * 2 + 192 * 1024 * 2;  // 6.68 MB

  // split factor: KS=4 (R11 measured best -- halves Opart/lpart traffic)
  int KS = 4;
  while (KS > 1 &&
         base + (size_t)KS * ((size_t)B_ * T_ * H_ * 4 + (size_t)B_ * T_ * 4) >
             ws_size)
    KS >>= 1;
  int kslog = (KS == 4) ? 2 : (KS == 2) ? 1 : 0;

  float* Opart = (float*)((char*)d_ws + base);          // [B*KS][T][64] fp32
  float* lpart = Opart + (size_t)KS * B_ * T_ * H_;     // [B*KS][T] fp32
  float* out = (float*)d_out;

  cast_w_kernel<<<dim3(192), 256, 0, stream>>>(Wq, Wk, Wv, Wb);
  proj9_kernel<<<dim3(256), 256, 0, stream>>>(x, Wb, Qb, Kb, Vt);
  attn_kernel<<<dim3(32, B_ * KS), 256, 0, stream>>>(Qb, Kb, Vt, Opart, lpart,
                                                     KS, kslog);
  combine_kernel<<<dim3(1024), 256, 0, stream>>>(Opart, lpart, out, KS, kslog);
}